// Round 2
// baseline (394.785 us; speedup 1.0000x reference)
//
#include <hip/hip_runtime.h>

// Problem constants (fixed): B=2, T=2048, C=1024, H=16, DQK=DV=64
// Inputs float32 (per reference), output float32. Internally bf16 MFMA.

typedef short bf16x8 __attribute__((ext_vector_type(8)));
typedef float f32x4 __attribute__((ext_vector_type(4)));

#define MFMA_BF16 __builtin_amdgcn_mfma_f32_16x16x32_bf16

__device__ __forceinline__ unsigned short f2bf(float f) {
    union { float f; unsigned u; } un; un.f = f;
    unsigned r = un.u + 0x7fffu + ((un.u >> 16) & 1u);  // RNE
    return (unsigned short)(r >> 16);
}
__device__ __forceinline__ unsigned pk2(float a, float b) {
    return (unsigned)f2bf(a) | ((unsigned)f2bf(b) << 16);
}

// C[4096 x 1024] = A[4096 x 1024] @ op(B)
// a_f32: A is fp32 (convert during staging) else bf16.
// b_layout 0: B fp32 [N=1024][K=1024] (K contiguous)  -> QKV weights
// b_layout 1: B fp32 [K=1024][N=1024] (N contiguous)  -> w_o
// out_mode 0: bf16 store at q-layout [(b*H+h)*T + t]*64 + d  (m=b*T+t, col=h*64+d)
// out_mode 1: fp32 store row-major [M,N]
__global__ __launch_bounds__(256) void gemm_bt(
    const void* __restrict__ Ap, const void* __restrict__ Bp,
    void* __restrict__ Cp, int a_f32, int b_layout, int out_mode)
{
    constexpr int K = 1024, N = 1024, P = 72;  // LDS pitch: b128 16B-aligned, 2-way-free banks
    __shared__ unsigned short lds_a[64 * P];
    __shared__ unsigned short lds_b[64 * P];
    const int tid = threadIdx.x;
    const int wave = tid >> 6, lane = tid & 63;
    const int l15 = lane & 15, l4 = lane >> 4;
    const int m0 = blockIdx.x << 6, n0 = blockIdx.y << 6;

    f32x4 acc[4] = {};

    for (int k0 = 0; k0 < K; k0 += 64) {
        // stage A tile (64x64)
        if (a_f32) {
            const float* A = (const float*)Ap;
            for (int vv = tid; vv < 512; vv += 256) {
                int row = vv >> 3, col = (vv & 7) << 3;
                const float* s = &A[(m0 + row) * K + k0 + col];
                float4 f0 = *(const float4*)s, f1 = *(const float4*)(s + 4);
                uint4 o;
                o.x = pk2(f0.x, f0.y); o.y = pk2(f0.z, f0.w);
                o.z = pk2(f1.x, f1.y); o.w = pk2(f1.z, f1.w);
                *(uint4*)&lds_a[row * P + col] = o;
            }
        } else {
            const unsigned short* A = (const unsigned short*)Ap;
            for (int vv = tid; vv < 512; vv += 256) {
                int row = vv >> 3, col = (vv & 7) << 3;
                *(uint4*)&lds_a[row * P + col] =
                    *(const uint4*)&A[(m0 + row) * K + k0 + col];
            }
        }
        // stage B tile (64x64) as lds_b[n][k], fp32 source
        {
            const float* Bm = (const float*)Bp;
            if (b_layout == 0) {
                for (int vv = tid; vv < 512; vv += 256) {
                    int row = vv >> 3, col = (vv & 7) << 3;
                    const float* s = &Bm[(n0 + row) * K + k0 + col];
                    float4 f0 = *(const float4*)s, f1 = *(const float4*)(s + 4);
                    uint4 o;
                    o.x = pk2(f0.x, f0.y); o.y = pk2(f0.z, f0.w);
                    o.z = pk2(f1.x, f1.y); o.w = pk2(f1.z, f1.w);
                    *(uint4*)&lds_b[row * P + col] = o;
                }
            } else {
                // B is [K,N]: transpose-stage so lds_b is [n][k]
                for (int vv = tid; vv < 512; vv += 256) {
                    int kr = vv >> 3, nc = (vv & 7) << 3;
                    const float* s = &Bm[(k0 + kr) * N + n0 + nc];
                    float4 f0 = *(const float4*)s, f1 = *(const float4*)(s + 4);
                    lds_b[(nc + 0) * P + kr] = f2bf(f0.x);
                    lds_b[(nc + 1) * P + kr] = f2bf(f0.y);
                    lds_b[(nc + 2) * P + kr] = f2bf(f0.z);
                    lds_b[(nc + 3) * P + kr] = f2bf(f0.w);
                    lds_b[(nc + 4) * P + kr] = f2bf(f1.x);
                    lds_b[(nc + 5) * P + kr] = f2bf(f1.y);
                    lds_b[(nc + 6) * P + kr] = f2bf(f1.z);
                    lds_b[(nc + 7) * P + kr] = f2bf(f1.w);
                }
            }
        }
        __syncthreads();
        #pragma unroll
        for (int ks = 0; ks < 2; ++ks) {
            bf16x8 a = *(const bf16x8*)&lds_a[(wave * 16 + l15) * P + ks * 32 + l4 * 8];
            #pragma unroll
            for (int ns = 0; ns < 4; ++ns) {
                bf16x8 b = *(const bf16x8*)&lds_b[(ns * 16 + l15) * P + ks * 32 + l4 * 8];
                acc[ns] = MFMA_BF16(a, b, acc[ns], 0, 0, 0);
            }
        }
        __syncthreads();
    }

    // epilogue: D row=(lane>>4)*4+reg, col=lane&15 (m89-verified)
    #pragma unroll
    for (int ns = 0; ns < 4; ++ns) {
        #pragma unroll
        for (int r = 0; r < 4; ++r) {
            int row = m0 + wave * 16 + l4 * 4 + r;
            int col = n0 + ns * 16 + l15;
            if (out_mode == 1) {
                ((float*)Cp)[row * N + col] = acc[ns][r];
            } else {
                int nb = row >> 11, t = row & 2047;   // T = 2048
                int hh = col >> 6, d = col & 63;      // D = 64
                ((unsigned short*)Cp)[(((nb << 4) + hh) * 2048 + t) * 64 + d] =
                    f2bf(acc[ns][r]);
            }
        }
    }
}

// Flash causal attention. q,k,v: [B,H,T,64] bf16. y: [B,T,H*64] bf16.
// One block per (q-tile of 64 rows, b*H+h). 4 waves; wave w owns q-rows w*16..w*16+15.
__global__ __launch_bounds__(256) void attn(
    const unsigned short* __restrict__ q,
    const unsigned short* __restrict__ k,
    const unsigned short* __restrict__ v,
    unsigned short* __restrict__ y)
{
    constexpr int P = 72;
    __shared__ unsigned short lds_q[64 * P];
    __shared__ unsigned short lds_k[64 * P];
    __shared__ unsigned short lds_vt[64 * P];  // transposed: [d][s]
    __shared__ unsigned short lds_p[64 * P];   // C-layout -> A-layout round-trip (m120)
    const int tid = threadIdx.x, wave = tid >> 6, lane = tid & 63;
    const int l15 = lane & 15, l4 = lane >> 4;
    const int qt = blockIdx.x, bh = blockIdx.y;
    const int nb = bh >> 4, hh = bh & 15;      // H = 16
    const int q0 = qt << 6;
    const int base = bh << 17;                 // bh * T * 64

    for (int vv = tid; vv < 512; vv += 256) {
        int row = vv >> 3, col = (vv & 7) << 3;
        *(uint4*)&lds_q[row * P + col] =
            *(const uint4*)&q[base + ((q0 + row) << 6) + col];
    }
    __syncthreads();
    bf16x8 qf[2];
    #pragma unroll
    for (int ks = 0; ks < 2; ++ks)
        qf[ks] = *(const bf16x8*)&lds_q[(wave * 16 + l15) * P + ks * 32 + l4 * 8];

    float m_run[4], l_run[4];
    f32x4 acc_o[4] = {};
    int row_g[4];
    #pragma unroll
    for (int r = 0; r < 4; ++r) {
        m_run[r] = -1e30f; l_run[r] = 0.f;
        row_g[r] = q0 + wave * 16 + l4 * 4 + r;
    }

    for (int st = 0; st <= qt; ++st) {
        const int s0 = st << 6;
        for (int vv = tid; vv < 512; vv += 256) {
            int row = vv >> 3, col = (vv & 7) << 3;
            *(uint4*)&lds_k[row * P + col] =
                *(const uint4*)&k[base + ((s0 + row) << 6) + col];
            uint4 d = *(const uint4*)&v[base + ((s0 + row) << 6) + col];
            unsigned short e[8] = {
                (unsigned short)(d.x & 0xffff), (unsigned short)(d.x >> 16),
                (unsigned short)(d.y & 0xffff), (unsigned short)(d.y >> 16),
                (unsigned short)(d.z & 0xffff), (unsigned short)(d.z >> 16),
                (unsigned short)(d.w & 0xffff), (unsigned short)(d.w >> 16)};
            #pragma unroll
            for (int j = 0; j < 8; ++j) lds_vt[(col + j) * P + row] = e[j];
        }
        __syncthreads();

        // S = Q K^T (16x64 per wave), fp32 acc
        f32x4 s_acc[4] = {};
        #pragma unroll
        for (int ks = 0; ks < 2; ++ks) {
            #pragma unroll
            for (int ns = 0; ns < 4; ++ns) {
                bf16x8 kf = *(const bf16x8*)&lds_k[(ns * 16 + l15) * P + ks * 32 + l4 * 8];
                s_acc[ns] = MFMA_BF16(qf[ks], kf, s_acc[ns], 0, 0, 0);
            }
        }

        const bool diag = (st == qt);
        #pragma unroll
        for (int r = 0; r < 4; ++r) {
            float sv[4];
            float mx = -1e30f;
            #pragma unroll
            for (int ns = 0; ns < 4; ++ns) {
                float x = s_acc[ns][r] * 0.125f;  // 1/sqrt(64)
                if (diag && (s0 + ns * 16 + l15) > row_g[r]) x = -1e30f;
                sv[ns] = x;
                mx = fmaxf(mx, x);
            }
            #pragma unroll
            for (int off = 1; off < 16; off <<= 1) mx = fmaxf(mx, __shfl_xor(mx, off));
            float mnew = fmaxf(m_run[r], mx);
            float alpha = __expf(m_run[r] - mnew);
            m_run[r] = mnew;
            float rsum = 0.f;
            #pragma unroll
            for (int ns = 0; ns < 4; ++ns) {
                float pv = __expf(sv[ns] - mnew);
                rsum += pv;
                lds_p[(wave * 16 + l4 * 4 + r) * P + ns * 16 + l15] = f2bf(pv);
            }
            #pragma unroll
            for (int off = 1; off < 16; off <<= 1) rsum += __shfl_xor(rsum, off);
            l_run[r] = l_run[r] * alpha + rsum;
            #pragma unroll
            for (int ds = 0; ds < 4; ++ds) acc_o[ds][r] *= alpha;
        }
        __syncthreads();

        // O += P V  (P in A-layout from LDS, V^T gives contiguous B-frags)
        #pragma unroll
        for (int ks = 0; ks < 2; ++ks) {
            bf16x8 pf = *(const bf16x8*)&lds_p[(wave * 16 + l15) * P + ks * 32 + l4 * 8];
            #pragma unroll
            for (int ds = 0; ds < 4; ++ds) {
                bf16x8 vf = *(const bf16x8*)&lds_vt[(ds * 16 + l15) * P + ks * 32 + l4 * 8];
                acc_o[ds] = MFMA_BF16(pf, vf, acc_o[ds], 0, 0, 0);
            }
        }
        __syncthreads();
    }

    #pragma unroll
    for (int ds = 0; ds < 4; ++ds) {
        #pragma unroll
        for (int r = 0; r < 4; ++r) {
            float val = acc_o[ds][r] / l_run[r];
            y[(((nb << 11) + row_g[r]) << 10) + (hh << 6) + ds * 16 + l15] = f2bf(val);
        }
    }
}

extern "C" void kernel_launch(void* const* d_in, const int* in_sizes, int n_in,
                              void* d_out, int out_size, void* d_ws, size_t ws_size,
                              hipStream_t stream) {
    const float* x  = (const float*)d_in[0];  // [2,2048,1024] fp32
    const float* wq = (const float*)d_in[1];  // [16,64,1024]  fp32
    const float* wk = (const float*)d_in[2];
    const float* wv = (const float*)d_in[3];
    const float* wo = (const float*)d_in[4];  // [1024,1024]   fp32
    float* out = (float*)d_out;               // [2,2048,1024] fp32

    const size_t QKV_ELEMS = 2u * 16u * 2048u * 64u;  // 4M bf16 elems each
    unsigned short* qbuf = (unsigned short*)d_ws;
    unsigned short* kbuf = qbuf + QKV_ELEMS;
    unsigned short* vbuf = kbuf + QKV_ELEMS;
    unsigned short* ybuf = vbuf + QKV_ELEMS;          // [B,T,H*64] bf16

    dim3 blk(256);
    gemm_bt<<<dim3(64, 16), blk, 0, stream>>>(x, wq, qbuf, 1, 0, 0);
    gemm_bt<<<dim3(64, 16), blk, 0, stream>>>(x, wk, kbuf, 1, 0, 0);
    gemm_bt<<<dim3(64, 16), blk, 0, stream>>>(x, wv, vbuf, 1, 0, 0);
    attn<<<dim3(32, 32), blk, 0, stream>>>(qbuf, kbuf, vbuf, ybuf);
    gemm_bt<<<dim3(64, 16), blk, 0, stream>>>(ybuf, wo, out, 0, 1, 1);
}

// Round 3
// 279.649 us; speedup vs baseline: 1.4117x; 1.4117x over previous
//
#include <hip/hip_runtime.h>

// B=2, T=2048, C=1024, H=16, DQK=DV=64. Inputs fp32, output fp32, bf16 MFMA inside.

typedef short bf16x8 __attribute__((ext_vector_type(8)));
typedef float f32x4 __attribute__((ext_vector_type(4)));

#define MFMA_BF16 __builtin_amdgcn_mfma_f32_16x16x32_bf16

__device__ __forceinline__ unsigned short f2bf(float f) {
    union { float f; unsigned u; } un; un.f = f;
    unsigned r = un.u + 0x7fffu + ((un.u >> 16) & 1u);  // RNE
    return (unsigned short)(r >> 16);
}
__device__ __forceinline__ unsigned pk2(float a, float b) {
    return (unsigned)f2bf(a) | ((unsigned)f2bf(b) << 16);
}

// async global->LDS, 16B per lane; lptr must be wave-uniform (HW adds lane*16)
__device__ __forceinline__ void gload16(const void* g, void* l) {
    __builtin_amdgcn_global_load_lds(
        (const __attribute__((address_space(1))) unsigned int*)g,
        (__attribute__((address_space(3))) unsigned int*)l, 16, 0, 0);
}

// ---------- fp32 -> bf16 elementwise (n multiple of 8) ----------
__global__ __launch_bounds__(256) void cvt(const float* __restrict__ s,
                                           unsigned short* __restrict__ d, int n) {
    int i = (blockIdx.x * 256 + threadIdx.x) * 8;
    if (i < n) {
        float4 f0 = *(const float4*)&s[i], f1 = *(const float4*)&s[i + 4];
        uint4 o;
        o.x = pk2(f0.x, f0.y); o.y = pk2(f0.z, f0.w);
        o.z = pk2(f1.x, f1.y); o.w = pk2(f1.z, f1.w);
        *(uint4*)&d[i] = o;
    }
}

// ---------- wo [K=1024][N=1024] fp32 -> wo_t [N][K] bf16 ----------
__global__ __launch_bounds__(256) void cvt_t(const float* __restrict__ s,
                                             unsigned short* __restrict__ d) {
    __shared__ unsigned short t[64 * 72];
    const int k0 = blockIdx.x << 6, n0 = blockIdx.y << 6;
    const int r = threadIdx.x >> 2, cg = (threadIdx.x & 3) << 4;
    const float* src = &s[(k0 + r) * 1024 + n0 + cg];
    #pragma unroll
    for (int j = 0; j < 16; j += 4) {
        float4 f = *(const float4*)&src[j];
        t[(cg + j + 0) * 72 + r] = f2bf(f.x);
        t[(cg + j + 1) * 72 + r] = f2bf(f.y);
        t[(cg + j + 2) * 72 + r] = f2bf(f.z);
        t[(cg + j + 3) * 72 + r] = f2bf(f.w);
    }
    __syncthreads();
    unsigned short* dst = &d[(n0 + r) * 1024 + k0 + cg];
    uint4 o0, o1;
    unsigned short* tr = &t[r * 72 + cg];
    unsigned v[16];
    #pragma unroll
    for (int j = 0; j < 16; ++j) v[j] = tr[j];
    o0.x = v[0] | (v[1] << 16);  o0.y = v[2] | (v[3] << 16);
    o0.z = v[4] | (v[5] << 16);  o0.w = v[6] | (v[7] << 16);
    o1.x = v[8] | (v[9] << 16);  o1.y = v[10] | (v[11] << 16);
    o1.z = v[12] | (v[13] << 16); o1.w = v[14] | (v[15] << 16);
    *(uint4*)&dst[0] = o0;
    *(uint4*)&dst[8] = o1;
}

// ---------- m97-style 128x128 bf16 GEMM, K=1024, lda=ldb=1024 ----------
// mode 0: QK fused: n0g<1024 -> B0/C0 (Q, scale 0.125), else B1/C1 (K, scale 1);
//         bf16 store in [b,h,t,d] layout (row=b*2048+t, col=h*64+d)
// mode 1: fp32 row-major store, ldc
// mode 2: bf16 row-major store, ldc
__global__ __launch_bounds__(256) void gemm128(
    const unsigned short* __restrict__ A,
    const unsigned short* __restrict__ B0,
    const unsigned short* __restrict__ B1,
    void* __restrict__ C0, void* __restrict__ C1,
    int mode, int ldc)
{
    __shared__ unsigned short sa[128 * 64];
    __shared__ unsigned short sb[128 * 64];
    const int tid = threadIdx.x, wave = tid >> 6, lane = tid & 63;
    const int l15 = lane & 15, l4 = lane >> 4;
    const int m0 = blockIdx.x << 7;
    const int n0g = blockIdx.y << 7;
    const unsigned short* Bm = B0;
    void* C = C0;
    int n0 = n0g;
    float sc = (mode == 0) ? 0.125f : 1.0f;
    if (mode == 0 && n0g >= 1024) { Bm = B1; C = C1; n0 = n0g - 1024; sc = 1.0f; }

    const int wm = (wave >> 1) << 6, wn = (wave & 1) << 6;
    const int lrow = lane >> 3, lcb = (lane & 7) << 3;

    f32x4 acc[4][4] = {};

    for (int k0 = 0; k0 < 1024; k0 += 64) {
        #pragma unroll
        for (int i = 0; i < 4; ++i) {
            int rbase = i * 32 + wave * 8;
            gload16(&A[(size_t)(m0 + rbase + lrow) * 1024 + k0 + lcb], &sa[rbase * 64]);
            gload16(&Bm[(size_t)(n0 + rbase + lrow) * 1024 + k0 + lcb], &sb[rbase * 64]);
        }
        __syncthreads();
        #pragma unroll
        for (int ks = 0; ks < 2; ++ks) {
            bf16x8 af[4], bf[4];
            #pragma unroll
            for (int i = 0; i < 4; ++i)
                af[i] = *(const bf16x8*)&sa[(wm + i * 16 + l15) * 64 + ks * 32 + l4 * 8];
            #pragma unroll
            for (int j = 0; j < 4; ++j)
                bf[j] = *(const bf16x8*)&sb[(wn + j * 16 + l15) * 64 + ks * 32 + l4 * 8];
            #pragma unroll
            for (int i = 0; i < 4; ++i)
                #pragma unroll
                for (int j = 0; j < 4; ++j)
                    acc[i][j] = MFMA_BF16(af[i], bf[j], acc[i][j], 0, 0, 0);
        }
        __syncthreads();
    }

    #pragma unroll
    for (int i = 0; i < 4; ++i) {
        #pragma unroll
        for (int j = 0; j < 4; ++j) {
            #pragma unroll
            for (int r = 0; r < 4; ++r) {
                int row = m0 + wm + i * 16 + l4 * 4 + r;
                int col = n0 + wn + j * 16 + l15;
                float val = acc[i][j][r];
                if (mode == 0) {
                    int nb = row >> 11, t = row & 2047;
                    int hh = col >> 6, dd = col & 63;
                    ((unsigned short*)C)[(((nb << 4) + hh) * 2048 + t) * 64 + dd] =
                        f2bf(val * sc);
                } else if (mode == 1) {
                    ((float*)C)[(size_t)row * ldc + col] = val;
                } else {
                    ((unsigned short*)C)[(size_t)row * ldc + col] = f2bf(val);
                }
            }
        }
    }
}

// ---------- flash causal attention ----------
// q,k: [B,H,T,64] bf16 (q pre-scaled by 0.125). vt: [H*64][B*T] bf16. y: [B*T][1024] bf16.
// 128 q-rows per block; wave w owns rows w*32..w*32+31 (2 m-frags).
__global__ __launch_bounds__(256) void attn(
    const unsigned short* __restrict__ q,
    const unsigned short* __restrict__ k,
    const unsigned short* __restrict__ vt,
    unsigned short* __restrict__ y)
{
    constexpr int P = 72;
    __shared__ unsigned short sq[128 * P];
    __shared__ unsigned short sk[64 * P];
    __shared__ unsigned short sv[64 * P];   // [d][s]
    __shared__ unsigned short sp[128 * P];  // wave-private C->A layout round-trip
    const int tid = threadIdx.x, wave = tid >> 6, lane = tid & 63;
    const int l15 = lane & 15, l4 = lane >> 4;
    const int bid = blockIdx.x;
    const int qt = 15 - (bid >> 5);         // descending: long blocks first
    const int bh = bid & 31;
    const int nb = bh >> 4, hh = bh & 15;
    const int q0 = qt << 7;
    const size_t base = (size_t)bh << 17;   // bh * T * 64

    for (int vv = tid; vv < 1024; vv += 256) {
        int row = vv >> 3, col = (vv & 7) << 3;
        *(uint4*)&sq[row * P + col] = *(const uint4*)&q[base + ((q0 + row) << 6) + col];
    }
    __syncthreads();
    bf16x8 qf[2][2];
    #pragma unroll
    for (int mi = 0; mi < 2; ++mi)
        #pragma unroll
        for (int ks = 0; ks < 2; ++ks)
            qf[mi][ks] = *(const bf16x8*)&sq[(wave * 32 + mi * 16 + l15) * P + ks * 32 + l4 * 8];

    float m_run[2][4], l_run[2][4];
    f32x4 acc_o[2][4] = {};
    int row_g[2][4];
    #pragma unroll
    for (int mi = 0; mi < 2; ++mi)
        #pragma unroll
        for (int r = 0; r < 4; ++r) {
            m_run[mi][r] = -1e30f; l_run[mi][r] = 0.f;
            row_g[mi][r] = q0 + wave * 32 + mi * 16 + l4 * 4 + r;
        }

    const int nst = 2 * qt + 2;
    for (int st = 0; st < nst; ++st) {
        const int s0 = st << 6;
        for (int vv = tid; vv < 512; vv += 256) {
            int row = vv >> 3, col = (vv & 7) << 3;
            *(uint4*)&sk[row * P + col] = *(const uint4*)&k[base + ((s0 + row) << 6) + col];
            *(uint4*)&sv[row * P + col] =
                *(const uint4*)&vt[(size_t)((hh << 6) + row) * 4096 + (nb << 11) + s0 + col];
        }
        __syncthreads();

        const bool diag = (st >= 2 * qt);
        #pragma unroll
        for (int mi = 0; mi < 2; ++mi) {
            f32x4 s_acc[4] = {};
            #pragma unroll
            for (int ks = 0; ks < 2; ++ks)
                #pragma unroll
                for (int ns = 0; ns < 4; ++ns) {
                    bf16x8 kf = *(const bf16x8*)&sk[(ns * 16 + l15) * P + ks * 32 + l4 * 8];
                    s_acc[ns] = MFMA_BF16(qf[mi][ks], kf, s_acc[ns], 0, 0, 0);
                }
            #pragma unroll
            for (int r = 0; r < 4; ++r) {
                float sv4[4], mx = -1e30f;
                #pragma unroll
                for (int ns = 0; ns < 4; ++ns) {
                    float x = s_acc[ns][r];
                    if (diag && (s0 + ns * 16 + l15) > row_g[mi][r]) x = -1e30f;
                    sv4[ns] = x; mx = fmaxf(mx, x);
                }
                #pragma unroll
                for (int off = 1; off < 16; off <<= 1) mx = fmaxf(mx, __shfl_xor(mx, off));
                float mnew = fmaxf(m_run[mi][r], mx);
                float alpha = __expf(m_run[mi][r] - mnew);
                m_run[mi][r] = mnew;
                float rsum = 0.f;
                #pragma unroll
                for (int ns = 0; ns < 4; ++ns) {
                    float pv = __expf(sv4[ns] - mnew);
                    rsum += pv;
                    sp[(wave * 32 + mi * 16 + l4 * 4 + r) * P + ns * 16 + l15] = f2bf(pv);
                }
                #pragma unroll
                for (int off = 1; off < 16; off <<= 1) rsum += __shfl_xor(rsum, off);
                l_run[mi][r] = l_run[mi][r] * alpha + rsum;
                #pragma unroll
                for (int ds = 0; ds < 4; ++ds) acc_o[mi][ds][r] *= alpha;
            }
        }
        // PV: sp is wave-private (same-wave DS ops are ordered) -> no barrier needed
        #pragma unroll
        for (int mi = 0; mi < 2; ++mi)
            #pragma unroll
            for (int ks = 0; ks < 2; ++ks) {
                bf16x8 pf = *(const bf16x8*)&sp[(wave * 32 + mi * 16 + l15) * P + ks * 32 + l4 * 8];
                #pragma unroll
                for (int ds = 0; ds < 4; ++ds) {
                    bf16x8 vf = *(const bf16x8*)&sv[(ds * 16 + l15) * P + ks * 32 + l4 * 8];
                    acc_o[mi][ds] = MFMA_BF16(pf, vf, acc_o[mi][ds], 0, 0, 0);
                }
            }
        __syncthreads();  // before next tile's staging overwrites sk/sv
    }

    #pragma unroll
    for (int mi = 0; mi < 2; ++mi)
        #pragma unroll
        for (int ds = 0; ds < 4; ++ds)
            #pragma unroll
            for (int r = 0; r < 4; ++r) {
                float val = acc_o[mi][ds][r] / l_run[mi][r];
                y[((size_t)((nb << 11) + row_g[mi][r]) << 10) + (hh << 6) + ds * 16 + l15] =
                    f2bf(val);
            }
}

extern "C" void kernel_launch(void* const* d_in, const int* in_sizes, int n_in,
                              void* d_out, int out_size, void* d_ws, size_t ws_size,
                              hipStream_t stream) {
    const float* x  = (const float*)d_in[0];  // [2,2048,1024]
    const float* wq = (const float*)d_in[1];  // [16,64,1024]
    const float* wk = (const float*)d_in[2];
    const float* wv = (const float*)d_in[3];
    const float* wo = (const float*)d_in[4];  // [1024,1024]
    float* out = (float*)d_out;               // [2,2048,1024] fp32

    const size_t M1 = 1u << 20;               // 1M elems
    unsigned short* x16  = (unsigned short*)d_ws;          // 4M
    unsigned short* wq16 = x16 + 4 * M1;                   // 1M
    unsigned short* wk16 = wq16 + M1;
    unsigned short* wv16 = wk16 + M1;
    unsigned short* wot  = wv16 + M1;                      // 1M (wo^T)
    unsigned short* qbuf = wot + M1;                       // 4M [B,H,T,64]
    unsigned short* kbuf = qbuf + 4 * M1;                  // 4M
    unsigned short* vtb  = kbuf + 4 * M1;                  // 4M [1024][4096]
    unsigned short* ybuf = vtb + 4 * M1;                   // 4M [4096][1024]

    dim3 blk(256);
    cvt<<<2048, blk, 0, stream>>>(x, x16, 4 * (int)M1);
    cvt<<<512, blk, 0, stream>>>(wq, wq16, (int)M1);
    cvt<<<512, blk, 0, stream>>>(wk, wk16, (int)M1);
    cvt<<<512, blk, 0, stream>>>(wv, wv16, (int)M1);
    cvt_t<<<dim3(16, 16), blk, 0, stream>>>(wo, wot);

    // Q,K projections fused: C=[4096,2048], Q cols scaled by 1/sqrt(64)
    gemm128<<<dim3(32, 16), blk, 0, stream>>>(x16, wq16, wk16, qbuf, kbuf, 0, 0);
    // V^T = Wv * X^T: C=[1024,4096] bf16 row-major
    gemm128<<<dim3(8, 32), blk, 0, stream>>>(wv16, x16, nullptr, vtb, nullptr, 2, 4096);

    attn<<<512, blk, 0, stream>>>(qbuf, kbuf, vtb, ybuf);

    // out = Y @ Wo: [4096,1024] fp32
    gemm128<<<dim3(32, 8), blk, 0, stream>>>(ybuf, wot, nullptr, out, nullptr, 1, 1024);
}